// Round 3
// baseline (2598.323 us; speedup 1.0000x reference)
//
#include <hip/hip_runtime.h>
#include <hip/hip_bf16.h>

typedef unsigned int uint;
typedef unsigned short ushort;
typedef unsigned long long ulong64;

typedef __bf16 bf16x8 __attribute__((ext_vector_type(8)));
typedef float f32x16 __attribute__((ext_vector_type(16)));

#define ITILE 62          // 32 + 31 - 1 input tile side
#define PIXB  40          // bytes per LDS pixel: 16ch bf16 = 32B data + 8B pad (bank spread)
#define LDS_BYTES (ITILE * ITILE * PIXB)   // 153760 < 160K

__device__ __forceinline__ ushort f2bf(float f) {
  uint x = __builtin_bit_cast(uint, f);
  x += 0x7fffu + ((x >> 16) & 1u);   // round-to-nearest-even
  return (ushort)(x >> 16);
}

struct U16B { ulong64 a, b; };
__device__ __forceinline__ bf16x8 lds_ld16(const char* p) {
  // 8B-aligned 16B LDS read (pixel stride 40B -> can't assume 16B align)
  U16B u;
  u.a = *(const ulong64*)(p);
  u.b = *(const ulong64*)(p + 8);
  return __builtin_bit_cast(bf16x8, u);
}

// ---------------- pre-pass 1: NCHW fp32 -> NHWC bf16 ----------------
// one thread per 16B output chunk (8 channels of one pixel)
extern "C" __global__ void cvt_sig(const float* __restrict__ in, ushort* __restrict__ out) {
  uint chunk = blockIdx.x * 256 + threadIdx.x;     // 16*256*256*4 = 4194304 total
  uint g = chunk & 3u;
  uint x = (chunk >> 2) & 255u;
  uint y = (chunk >> 10) & 255u;
  uint b = chunk >> 18;
  const float* src = in + (((size_t)b * 32 + g * 8) * 256 + y) * 256 + x;
  uint w0 = (uint)f2bf(src[0])        | ((uint)f2bf(src[1 * 65536]) << 16);
  uint w1 = (uint)f2bf(src[2 * 65536]) | ((uint)f2bf(src[3 * 65536]) << 16);
  uint w2 = (uint)f2bf(src[4 * 65536]) | ((uint)f2bf(src[5 * 65536]) << 16);
  uint w3 = (uint)f2bf(src[6 * 65536]) | ((uint)f2bf(src[7 * 65536]) << 16);
  *(uint4*)(out + (size_t)chunk * 8) = make_uint4(w0, w1, w2, w3);
}

// ---------------- pre-pass 2: weights -> bf16 B-fragment layout ----------------
// wt[half][kk][chunk j][i]  where j: col=j&31 (=cout), g=j>>5 ; element i: c = half*16+g*8+i
extern "C" __global__ void cvt_wt(const float* __restrict__ w, ushort* __restrict__ wt) {
  uint tid = blockIdx.x * 256 + threadIdx.x;       // 2*961*512 = 984064 total
  uint i = tid & 7u;
  uint j = (tid >> 3) & 63u;
  uint rest = tid >> 9;                             // < 1922
  uint kk = rest % 961u;
  uint h  = rest / 961u;
  uint col = j & 31u;
  uint g   = j >> 5;
  uint c = h * 16u + g * 8u + i;
  uint ky = kk / 31u, kx = kk - ky * 31u;
  wt[tid] = f2bf(w[((col * 32u + c) * 31u + ky) * 31u + kx]);
}

// ---------------- main conv: 32x32 output tile, 8 waves, mfma 32x32x16 bf16 ----------------
extern "C" __global__ void __launch_bounds__(512, 2)
conv_main(const ushort* __restrict__ sigbf, const char* __restrict__ wtbf,
          const float* __restrict__ bias, float* __restrict__ out) {
  extern __shared__ char lds[];
  const int tid = threadIdx.x;
  const int lane = tid & 63;
  const int wv  = tid >> 6;        // 0..7, owns output rows wv*4 .. wv*4+3
  const int l31 = lane & 31;       // = M row (ox offset) for A, = cout col for B/C
  const int hi  = lane >> 5;       // k-half selector of the fragment
  const int ox0 = blockIdx.x * 32, oy0 = blockIdx.y * 32;
  const int bb = blockIdx.z;

  f32x16 acc[4];
#pragma unroll
  for (int t = 0; t < 4; ++t)
#pragma unroll
    for (int i = 0; i < 16; ++i) acc[t][i] = 0.0f;

  for (int h = 0; h < 2; ++h) {     // two 16-channel halves; acc persists
    if (h) __syncthreads();         // previous half's compute done before overwrite
    // ---- stage input tile half: 62*62 pixels * 16ch bf16, pixel stride 40B ----
    for (int it = 0; it < 16; ++it) {
      int c = it * 512 + tid;
      if (c < ITILE * ITILE * 2) {
        int p = c >> 1, sub = c & 1;
        int ty = p / ITILE;
        int tx = p - ty * ITILE;
        int gy = oy0 + ty; gy = gy > 255 ? 255 : gy;   // clamp (only invalid outputs use it)
        int gx = ox0 + tx; gx = gx > 255 ? 255 : gx;
        const uint4* src = (const uint4*)(sigbf +
            ((((size_t)bb << 8) + gy) * 256 + gx) * 32 + h * 16 + sub * 8);
        uint4 v = *src;
        char* dst = lds + p * PIXB + sub * 16;
        *(uint2*)(dst)     = make_uint2(v.x, v.y);
        *(uint2*)(dst + 8) = make_uint2(v.z, v.w);
      }
    }
    __syncthreads();

    // ---- 961-tap K loop, barrier-free; B fragments stream from global (L1/L2-hot) ----
    const char* wb = wtbf + (size_t)h * 961 * 1024;
    bf16x8 bfrag = *(const bf16x8*)(wb + lane * 16);
    for (int ky = 0; ky < 31; ++ky) {
      const char* abase = lds + (((wv * 4 + ky) * ITILE) + l31) * PIXB + hi * 16;
#pragma unroll
      for (int kx = 0; kx < 31; ++kx) {
        int kk = ky * 31 + kx;
        int nk = (kk + 1 < 961) ? kk + 1 : 960;
        bf16x8 bnext = *(const bf16x8*)(wb + (size_t)nk * 1024 + lane * 16);
#pragma unroll
        for (int t = 0; t < 4; ++t) {
          bf16x8 a = lds_ld16(abase + t * (4 * ITILE * PIXB / 4) + kx * PIXB);
          acc[t] = __builtin_amdgcn_mfma_f32_32x32x16_bf16(a, bfrag, acc[t], 0, 0, 0);
        }
        bfrag = bnext;
      }
    }
  }

  // ---- epilogue: C/D layout col=lane&31 (=cout), row=(r&3)+8*(r>>2)+4*hi (=ox) ----
  float bv = bias[l31];
#pragma unroll
  for (int t = 0; t < 4; ++t) {
    int oy = oy0 + wv * 4 + t;
    if (oy >= 226) continue;
    size_t ob = (((size_t)bb * 32 + l31) * 226 + oy) * 226;
#pragma unroll
    for (int q = 0; q < 4; ++q) {
      int ox = ox0 + q * 8 + hi * 4;
      float4 v = make_float4(acc[t][4 * q + 0] + bv, acc[t][4 * q + 1] + bv,
                             acc[t][4 * q + 2] + bv, acc[t][4 * q + 3] + bv);
      if (ox + 3 < 226) {
        *(float4*)(out + ob + ox) = v;   // dwordx4 needs only 4B align on gfx9
      } else {
        if (ox + 0 < 226) out[ob + ox + 0] = v.x;
        if (ox + 1 < 226) out[ob + ox + 1] = v.y;
        if (ox + 2 < 226) out[ob + ox + 2] = v.z;
        if (ox + 3 < 226) out[ob + ox + 3] = v.w;
      }
    }
  }
}

extern "C" void kernel_launch(void* const* d_in, const int* in_sizes, int n_in,
                              void* d_out, int out_size, void* d_ws, size_t ws_size,
                              hipStream_t stream) {
  const float* sig = (const float*)d_in[0];
  const float* wgt = (const float*)d_in[1];
  const float* bia = (const float*)d_in[2];
  float* out = (float*)d_out;
  ushort* sigbf = (ushort*)d_ws;                       // 16*256*256*32 bf16 = 64 MiB
  char*   wtbf  = (char*)d_ws + 67108864;              // 2*961*1024 B ~ 1.9 MiB

  // allow >64KB dynamic LDS (ignore error if unsupported/no-op on ROCm)
  (void)hipFuncSetAttribute(reinterpret_cast<const void*>(conv_main),
                            hipFuncAttributeMaxDynamicSharedMemorySize, LDS_BYTES);

  cvt_sig<<<16384, 256, 0, stream>>>(sig, sigbf);
  cvt_wt<<<3844, 256, 0, stream>>>(wgt, (ushort*)wtbf);
  conv_main<<<dim3(8, 8, 16), 512, LDS_BYTES, stream>>>(sigbf, wtbf, bia, out);

  (void)in_sizes; (void)n_in; (void)out_size; (void)ws_size;
}

// Round 5
// 1773.170 us; speedup vs baseline: 1.4654x; 1.4654x over previous
//
#include <hip/hip_runtime.h>
#include <hip/hip_bf16.h>

typedef unsigned int uint;
typedef unsigned short ushort;

typedef __bf16 bf16x8 __attribute__((ext_vector_type(8)));
typedef float f32x16 __attribute__((ext_vector_type(16)));

#define ITX   62                 // input tile width (32 + 31 - 1)
#define ROWB  (ITX * 32)         // 1984 B per LDS row (62 px * 16ch * 2B)
#define LROWS 64                 // 63 staged rows + 1 ring-spill row
#define LDS_BYTES (LROWS * ROWB) // 126976 < 160K

#define MFMA32(a, b, c) __builtin_amdgcn_mfma_f32_32x32x16_bf16((a), (b), (c), 0, 0, 0)

__device__ __forceinline__ ushort f2bf(float f) {
  uint x = __builtin_bit_cast(uint, f);
  x += 0x7fffu + ((x >> 16) & 1u);   // round-to-nearest-even
  return (ushort)(x >> 16);
}

// ---------------- pre-pass 1: NCHW fp32 -> NHWC bf16 (unchanged) ----------------
extern "C" __global__ void cvt_sig(const float* __restrict__ in, ushort* __restrict__ out) {
  uint chunk = blockIdx.x * 256 + threadIdx.x;     // 16*256*256*4 = 4194304 total
  uint g = chunk & 3u;
  uint x = (chunk >> 2) & 255u;
  uint y = (chunk >> 10) & 255u;
  uint b = chunk >> 18;
  const float* src = in + (((size_t)b * 32 + g * 8) * 256 + y) * 256 + x;
  uint w0 = (uint)f2bf(src[0])         | ((uint)f2bf(src[1 * 65536]) << 16);
  uint w1 = (uint)f2bf(src[2 * 65536]) | ((uint)f2bf(src[3 * 65536]) << 16);
  uint w2 = (uint)f2bf(src[4 * 65536]) | ((uint)f2bf(src[5 * 65536]) << 16);
  uint w3 = (uint)f2bf(src[6 * 65536]) | ((uint)f2bf(src[7 * 65536]) << 16);
  *(uint4*)(out + (size_t)chunk * 8) = make_uint4(w0, w1, w2, w3);
}

// ---------------- pre-pass 2: weights -> bf16, layout wt[h][kx][ky(32, pad0)][frag] ----
// flat ushort idx = (((h*31+kx)*32 + ky)*64 + j)*8 + i ; j: col=j&31 (cout), g=j>>5
// element i: c = h*16 + g*8 + i ; ky==31 is a zero pad line.
extern "C" __global__ void cvt_wt(const float* __restrict__ w, ushort* __restrict__ wt) {
  uint tid = blockIdx.x * 256 + threadIdx.x;       // 2*31*32*512 = 1015808 total
  uint i = tid & 7u;
  uint j = (tid >> 3) & 63u;
  uint rest = tid >> 9;                            // < 1984
  uint ky = rest & 31u;
  uint kxh = rest >> 5;                            // < 62
  uint kx = kxh % 31u;
  uint h  = kxh / 31u;
  uint col = j & 31u;
  uint g   = j >> 5;
  uint c = h * 16u + g * 8u + i;
  float v = 0.0f;
  if (ky < 31u) v = w[((col * 32u + c) * 31u + ky) * 31u + kx];
  wt[tid] = f2bf(v);
}

// ---------------- main conv: 32x32 tile, 8 waves, kx-outer / ky-inner A-ring ----------------
extern "C" __global__ void __launch_bounds__(512, 2)
conv_main(const ushort* __restrict__ sigbf, const char* __restrict__ wtbf,
          const float* __restrict__ bias, float* __restrict__ out) {
  extern __shared__ char lds[];
  const int tid = threadIdx.x;
  const int lane = tid & 63;
  const int wv  = tid >> 6;        // 0..7, owns output rows wv*4 .. wv*4+3
  const int l31 = lane & 31;       // = M row (ox offset) for A, = cout col for B/C
  const int hi  = lane >> 5;       // k-half selector of the fragment
  const int ox0 = blockIdx.x * 32, oy0 = blockIdx.y * 32;
  const int bb = blockIdx.z;

  f32x16 acc0, acc1, acc2, acc3;
#pragma unroll
  for (int i = 0; i < 16; ++i) { acc0[i] = 0.f; acc1[i] = 0.f; acc2[i] = 0.f; acc3[i] = 0.f; }

  for (int h = 0; h < 2; ++h) {     // two 16-channel halves; acc persists
    if (h) __syncthreads();         // previous half's compute done before overwrite
    // ---- stage input tile half: 63*62 pixels * 16ch bf16, XOR-swizzled 16B chunks ----
#pragma unroll
    for (int it = 0; it < 16; ++it) {
      int c = it * 512 + tid;
      if (c < 63 * 62 * 2) {
        int p = c >> 1, sub = c & 1;
        int ty = p / ITX;
        int tx = p - ty * ITX;
        int gy = oy0 + ty; gy = gy > 255 ? 255 : gy;   // clamp: only feeds discarded outputs
        int gx = ox0 + tx; gx = gx > 255 ? 255 : gx;
        uint4 v = *(const uint4*)(sigbf +
            ((((size_t)bb << 8) + gy) * 256 + gx) * 32 + h * 16 + sub * 8);
        uint off = (uint)(ty * ROWB + tx * 32 + sub * 16);
        off ^= (((uint)(tx >> 2)) & 1u) << 4;          // bank-spread swizzle (16B slot)
        *(uint4*)(lds + off) = v;
      }
    }
    __syncthreads();

    const char* wcol = wtbf + (((size_t)h * 31) << 15);
#pragma unroll 1
    for (int kx = 0; kx < 31; ++kx) {
      const char* wb = wcol + ((size_t)kx << 15);      // 32KB contiguous ky-column
      int col = l31 + kx;                              // 0..61
      uint apix = ((uint)col * 32u + (uint)hi * 16u) ^ (((uint)(col >> 2) & 1u) << 4);
      const char* ab = lds + (uint)(wv * 4) * ROWB + apix;
      // A ring init: rows wv*4 + 0..3 (slot = row mod 4)
      bf16x8 r0 = *(const bf16x8*)(ab + 0 * ROWB);
      bf16x8 r1 = *(const bf16x8*)(ab + 1 * ROWB);
      bf16x8 r2 = *(const bf16x8*)(ab + 2 * ROWB);
      bf16x8 r3 = *(const bf16x8*)(ab + 3 * ROWB);
      bf16x8 b0 = *(const bf16x8*)(wb + lane * 16);    // B line ky=0
      bf16x8 b1;
      const char* lb = ab + 4 * ROWB;                  // reload base (row ky+4 at ky=0)
#pragma unroll
      for (int g = 0; g < 8; ++g) {                    // 8 groups x 4 ky = 32 taps (ky=31 pad)
        const char* wbp = wb + g * 4096;
        const char* lbp = lb + (size_t)g * 4 * ROWB;
        const int ky = g * 4;                          // compile-time (g unrolled)
        // ---- J = 0 : rows ky..ky+3 in r0,r1,r2,r3 ----
        if (ky + 0 < 31) b1 = *(const bf16x8*)(wbp + 1 * 1024 + lane * 16);
        acc0 = MFMA32(r0, b0, acc0);
        acc1 = MFMA32(r1, b0, acc1);
        acc2 = MFMA32(r2, b0, acc2);
        acc3 = MFMA32(r3, b0, acc3);
        r0 = *(const bf16x8*)(lbp + 0 * ROWB);         // row ky+4 -> slot 0
        // ---- J = 1 : rows in r1,r2,r3,r0 ----
        if (ky + 1 < 31) b0 = *(const bf16x8*)(wbp + 2 * 1024 + lane * 16);
        acc0 = MFMA32(r1, b1, acc0);
        acc1 = MFMA32(r2, b1, acc1);
        acc2 = MFMA32(r3, b1, acc2);
        acc3 = MFMA32(r0, b1, acc3);
        r1 = *(const bf16x8*)(lbp + 1 * ROWB);         // row ky+5 -> slot 1
        // ---- J = 2 : rows in r2,r3,r0,r1 ----
        if (ky + 2 < 31) b1 = *(const bf16x8*)(wbp + 3 * 1024 + lane * 16);
        acc0 = MFMA32(r2, b0, acc0);
        acc1 = MFMA32(r3, b0, acc1);
        acc2 = MFMA32(r0, b0, acc2);
        acc3 = MFMA32(r1, b0, acc3);
        r2 = *(const bf16x8*)(lbp + 2 * ROWB);         // row ky+6 -> slot 2
        // ---- J = 3 : rows in r3,r0,r1,r2 ----
        if (ky + 3 < 31) b0 = *(const bf16x8*)(wbp + 4 * 1024 + lane * 16);
        acc0 = MFMA32(r3, b1, acc0);
        acc1 = MFMA32(r0, b1, acc1);
        acc2 = MFMA32(r1, b1, acc2);
        acc3 = MFMA32(r2, b1, acc3);
        r3 = *(const bf16x8*)(lbp + 3 * ROWB);         // row ky+7 -> slot 3 (last: spill row, unused)
      }
    }
  }

  // ---- epilogue: C/D layout col=lane&31 (=cout), row=(r&3)+8*(r>>2)+4*hi (=ox) ----
  float bv = bias[l31];
  f32x16 accv[4] = {acc0, acc1, acc2, acc3};
#pragma unroll
  for (int t = 0; t < 4; ++t) {
    int oy = oy0 + wv * 4 + t;
    if (oy >= 226) continue;
    size_t ob = (((size_t)bb * 32 + l31) * 226 + oy) * 226;
#pragma unroll
    for (int q = 0; q < 4; ++q) {
      int ox = ox0 + q * 8 + hi * 4;
      float4 v = make_float4(accv[t][4 * q + 0] + bv, accv[t][4 * q + 1] + bv,
                             accv[t][4 * q + 2] + bv, accv[t][4 * q + 3] + bv);
      if (ox + 3 < 226) {
        *(float4*)(out + ob + ox) = v;
      } else {
        if (ox + 0 < 226) out[ob + ox + 0] = v.x;
        if (ox + 1 < 226) out[ob + ox + 1] = v.y;
        if (ox + 2 < 226) out[ob + ox + 2] = v.z;
        if (ox + 3 < 226) out[ob + ox + 3] = v.w;
      }
    }
  }
}

extern "C" void kernel_launch(void* const* d_in, const int* in_sizes, int n_in,
                              void* d_out, int out_size, void* d_ws, size_t ws_size,
                              hipStream_t stream) {
  const float* sig = (const float*)d_in[0];
  const float* wgt = (const float*)d_in[1];
  const float* bia = (const float*)d_in[2];
  float* out = (float*)d_out;
  ushort* sigbf = (ushort*)d_ws;                       // 16*256*256*32 bf16 = 64 MiB
  char*   wtbf  = (char*)d_ws + 67108864;              // 2*31*32KB = 1.94 MiB

  (void)hipFuncSetAttribute(reinterpret_cast<const void*>(conv_main),
                            hipFuncAttributeMaxDynamicSharedMemorySize, LDS_BYTES);

  cvt_sig<<<16384, 256, 0, stream>>>(sig, sigbf);
  cvt_wt<<<3968, 256, 0, stream>>>(wgt, (ushort*)wtbf);
  conv_main<<<dim3(8, 8, 16), 512, LDS_BYTES, stream>>>(sigbf, wtbf, bia, out);

  (void)in_sizes; (void)n_in; (void)out_size; (void)ws_size;
}